// Round 18
// baseline (198.586 us; speedup 1.0000x reference)
//
#include <hip/hip_runtime.h>
#include <hip/hip_bf16.h>

typedef __attribute__((ext_vector_type(8))) short short8;
typedef __attribute__((ext_vector_type(4))) float f32x4;

#define MFMA16(a, b, c) __builtin_amdgcn_mfma_f32_16x16x32_bf16((a), (b), (c), 0, 0, 0)

__device__ __forceinline__ unsigned short f2bf(float x) {
    union { float f; unsigned int u; } v; v.f = x;
    unsigned int u = v.u;
    return (unsigned short)((u + 0x7FFFu + ((u >> 16) & 1u)) >> 16);
}

__device__ __forceinline__ float pow14(float x) {
    return exp2f(1.4f * log2f(x));
}

__device__ __forceinline__ short8 ld8(const unsigned short* p) {
    return *reinterpret_cast<const short8*>(p);
}

__device__ __forceinline__ void gld16(const void* src, const unsigned char* dst) {
    __builtin_amdgcn_global_load_lds(
        (const __attribute__((address_space(1))) void*)src,
        (__attribute__((address_space(3))) void*)dst, 16, 0, 0);
}

// ---- K0: bbn fp32 -> bf16 (plain + row-swizzled copy), row sums s[i] ---------
__global__ void k_prep_bbn(const float* __restrict__ bbn, unsigned short* __restrict__ bbn_h,
                           unsigned short* __restrict__ bbn_swz, float* __restrict__ s) {
    int row = blockIdx.x * 4 + (threadIdx.x >> 6);
    int lane = threadIdx.x & 63;
    float x = bbn[row * 64 + lane];
    unsigned short h = f2bf(x);
    bbn_h[row * 64 + lane] = h;
    bbn_swz[row * 64 + (lane ^ ((row & 7) << 3))] = h;
    float v = x;
    #pragma unroll
    for (int m = 1; m < 64; m <<= 1) v += __shfl_xor(v, m);
    if (lane == 0) s[row] = v;
}

// ---- K0b/K2: transpose (+optional rsqrt(d) row scale, optional swizzle) ------
__global__ void k_transpose_scale(const float* __restrict__ in, unsigned short* __restrict__ out,
                                  const float* __restrict__ dvec, int K, int N, int swz) {
    __shared__ float tile[64][65];
    int tiles_k = K >> 6;
    int tk = blockIdx.x % tiles_k, tn = blockIdx.x / tiles_k;
    int k0 = tk * 64, n0 = tn * 64;
    int c = threadIdx.x & 63, rq = threadIdx.x >> 6;
    #pragma unroll
    for (int i = 0; i < 16; ++i) {
        int r = rq + 4 * i;
        float sc = dvec ? rsqrtf(dvec[k0 + r]) : 1.0f;
        tile[r][c] = in[(size_t)(k0 + r) * N + n0 + c] * sc;
    }
    __syncthreads();
    #pragma unroll
    for (int i = 0; i < 16; ++i) {
        int r = rq + 4 * i;
        int cc = swz ? (c ^ ((r & 7) << 3)) : c;
        out[(size_t)(n0 + r) * K + k0 + cc] = f2bf(tile[c][r]);
    }
}

// ---- K1: symmetric A materialization + degree partials ------------------------
// One 64x64 tile (ti,tj), ti<=tj, per block; 8256 blocks, 256 thr (4 waves).
// Off-diag tiles written twice (direct + LDS-transposed, matching swizzle).
// Degree: row-sums -> dpart[tj][i-strip] (race-free per-lane);
// col-sums -> per-wave partials in colbuf, cross-wave LDS reduction after the
// barrier, then single write dpart[ti][j-strip] (r17's 4-wave race FIXED).
__global__ __launch_bounds__(256, 4) void k_gen_adj(const unsigned short* __restrict__ bbn_h,
                                                    const unsigned short* __restrict__ bbn_swz,
                                                    const float* __restrict__ s,
                                                    unsigned short* __restrict__ A_swz,
                                                    float* __restrict__ dpart) {
    int bx = blockIdx.x;
    // triangular decode: f(ti) = ti*(257-ti)/2
    int ti = (int)((257.0f - sqrtf(66049.0f - 8.0f * (float)bx)) * 0.5f);
    while (ti * (257 - ti) / 2 > bx) --ti;
    while ((ti + 1) * (256 - ti) / 2 <= bx) ++ti;
    int tj = ti + (bx - ti * (257 - ti) / 2);
    int i0 = ti * 64, jbase = tj * 64;

    int tid = threadIdx.x;
    int w = tid >> 6, l = tid & 63, g = l >> 4, c = l & 15;

    __shared__ __align__(16) unsigned char Ajlds[8192];
    __shared__ __align__(16) unsigned char Outlds[8192];
    __shared__ float colbuf[4][64];

    // stage Aj rows (pre-swizzled source -> linear LDS)
    gld16(bbn_swz + (jbase + w * 8 + (l >> 3)) * 64 + (l & 7) * 8, &Ajlds[w * 1024]);
    gld16(bbn_swz + (jbase + 32 + w * 8 + (l >> 3)) * 64 + (l & 7) * 8, &Ajlds[4096 + w * 1024]);

    const unsigned short* ap = bbn_h + (i0 + w * 16 + c) * 64;
    short8 ga0 = ld8(ap), ga1 = ld8(ap + 32);
    float si = s[i0 + w * 16 + c];
    f32x4 sj4_0 = *reinterpret_cast<const f32x4*>(s + jbase + 0 * 16 + g * 4);
    f32x4 sj4_1 = *reinterpret_cast<const f32x4*>(s + jbase + 1 * 16 + g * 4);
    f32x4 sj4_2 = *reinterpret_cast<const f32x4*>(s + jbase + 2 * 16 + g * 4);
    f32x4 sj4_3 = *reinterpret_cast<const f32x4*>(s + jbase + 3 * 16 + g * 4);

    asm volatile("s_waitcnt vmcnt(0) lgkmcnt(0)\ns_barrier" ::: "memory");

    const int sw = (c & 7) << 4;
    float racc = 0.f;

#define GEN_SUB(GJ, SJ4) do {                                                      \
    short8 gb0 = *reinterpret_cast<const short8*>(                                 \
        &Ajlds[((GJ) * 16 + c) * 128 + ((g * 16) ^ sw)]);                          \
    short8 gb1 = *reinterpret_cast<const short8*>(                                 \
        &Ajlds[((GJ) * 16 + c) * 128 + ((64 + g * 16) ^ sw)]);                     \
    f32x4 gf = {0.f, 0.f, 0.f, 0.f};                                               \
    gf = MFMA16(gb0, ga0, gf);                                                     \
    gf = MFMA16(gb1, ga1, gf);                                                     \
    float t0 = fmaf(2.f, gf[0], -(si + (SJ4)[0]));                                 \
    float t1 = fmaf(2.f, gf[1], -(si + (SJ4)[1]));                                 \
    float t2 = fmaf(2.f, gf[2], -(si + (SJ4)[2]));                                 \
    float t3 = fmaf(2.f, gf[3], -(si + (SJ4)[3]));                                 \
    float u0 = pow14(fmaxf(fmaf(fabsf(t0), -0.015625f, 1.f), 0.f));                \
    float u1 = pow14(fmaxf(fmaf(fabsf(t1), -0.015625f, 1.f), 0.f));                \
    float u2 = pow14(fmaxf(fmaf(fabsf(t2), -0.015625f, 1.f), 0.f));                \
    float u3 = pow14(fmaxf(fmaf(fabsf(t3), -0.015625f, 1.f), 0.f));                \
    racc += (u0 + u1) + (u2 + u3);                                                 \
    if (ti != tj) {  /* per-wave partial column sums over this wave's 16 i's */    \
        float s0 = u0, s1 = u1, s2 = u2, s3 = u3;                                  \
        s0 += __shfl_xor(s0, 1); s0 += __shfl_xor(s0, 2);                          \
        s0 += __shfl_xor(s0, 4); s0 += __shfl_xor(s0, 8);                          \
        s1 += __shfl_xor(s1, 1); s1 += __shfl_xor(s1, 2);                          \
        s1 += __shfl_xor(s1, 4); s1 += __shfl_xor(s1, 8);                          \
        s2 += __shfl_xor(s2, 1); s2 += __shfl_xor(s2, 2);                          \
        s2 += __shfl_xor(s2, 4); s2 += __shfl_xor(s2, 8);                          \
        s3 += __shfl_xor(s3, 1); s3 += __shfl_xor(s3, 2);                          \
        s3 += __shfl_xor(s3, 4); s3 += __shfl_xor(s3, 8);                          \
        if (c == 0) {                                                              \
            f32x4 cs = {s0, s1, s2, s3};                                           \
            *reinterpret_cast<f32x4*>(&colbuf[w][(GJ) * 16 + g * 4]) = cs;         \
        }                                                                          \
    }                                                                              \
    unsigned short p0 = f2bf(u0), p1 = f2bf(u1), p2 = f2bf(u2), p3 = f2bf(u3);     \
    *reinterpret_cast<uint2*>(                                                     \
        &Outlds[(((w * 16 + c) * 128 + ((GJ) * 16 + g * 4) * 2) ^ sw)]) =          \
        make_uint2((unsigned)p0 | ((unsigned)p1 << 16),                            \
                   (unsigned)p2 | ((unsigned)p3 << 16));                           \
} while (0)

    GEN_SUB(0, sj4_0);
    GEN_SUB(1, sj4_1);
    GEN_SUB(2, sj4_2);
    GEN_SUB(3, sj4_3);
#undef GEN_SUB

    // row sums -> dpart[tj][i-strip] (per-lane addresses, race-free)
    racc += __shfl_xor(racc, 16);
    racc += __shfl_xor(racc, 32);
    if (g == 0) dpart[(size_t)tj * 8192 + i0 + w * 16 + c] = racc;

    asm volatile("s_waitcnt lgkmcnt(0)\ns_barrier" ::: "memory");

    // cross-wave col-sum reduction -> dpart[ti][j-strip] (single writer)
    if (ti != tj && tid < 64) {
        float v = colbuf[0][tid] + colbuf[1][tid] + colbuf[2][tid] + colbuf[3][tid];
        dpart[(size_t)ti * 8192 + jbase + tid] = v;
    }

    // direct writeback: Outlds layout == A_swz row layout (both swizzled)
    {
        int row = tid >> 2, seg = tid & 3;
        uint4 v0 = *reinterpret_cast<const uint4*>(&Outlds[tid * 32]);
        uint4 v1 = *reinterpret_cast<const uint4*>(&Outlds[tid * 32 + 16]);
        unsigned short* dst = A_swz + (size_t)(i0 + row) * 8192 + jbase + seg * 16;
        *reinterpret_cast<uint4*>(dst) = v0;
        *reinterpret_cast<uint4*>(dst + 8) = v1;
    }
    // transposed writeback (off-diagonal only)
    if (ti != tj) {
        int jt = tid >> 2, grp = tid & 3;
        int Xj = (jt & 7) << 3;
        #pragma unroll
        for (int hh = 0; hh < 2; ++hh) {
            unsigned short vv[8];
            #pragma unroll
            for (int e = 0; e < 8; ++e) {
                int it = grp * 16 + hh * 8 + e;
                vv[e] = *reinterpret_cast<const unsigned short*>(
                    &Outlds[it * 128 + ((jt * 2) ^ ((it & 7) << 4))]);
            }
            uint4 pk = make_uint4(
                (unsigned)vv[0] | ((unsigned)vv[1] << 16),
                (unsigned)vv[2] | ((unsigned)vv[3] << 16),
                (unsigned)vv[4] | ((unsigned)vv[5] << 16),
                (unsigned)vv[6] | ((unsigned)vv[7] << 16));
            *reinterpret_cast<uint4*>(
                A_swz + (size_t)(jbase + jt) * 8192 + i0 + ((grp * 16 + hh * 8) ^ Xj)) = pk;
        }
    }
}

// ---- K1b: d[i] = sum over 128 contributors of dpart[c][i] --------------------
__global__ __launch_bounds__(256) void k_degree_sum(const float* __restrict__ dpart,
                                                    float* __restrict__ dd) {
    int i = blockIdx.x * 256 + threadIdx.x;
    float v = 0.f;
    for (int cb = 0; cb < 128; ++cb) v += dpart[(size_t)cb * 8192 + i];
    dd[i] = v;
}

// ---- K3: split-K GEMM, BM=64 x BN=512 (full width), Ksplit=4 ------------------
__global__ __launch_bounds__(512, 4) void k_spectral(const unsigned short* __restrict__ A_swz,
                                                     const unsigned short* __restrict__ cbn_sT,
                                                     float* __restrict__ hpart) {
    int bx = blockIdx.x;
    int row = bx >> 2, ks = bx & 3;
    int i0 = row * 64, k0 = ks * 2048;

    int tid = threadIdx.x;
    int w = tid >> 6, l = tid & 63, g = l >> 4, c = l & 15;
    int lrow = l >> 3, lseg = l & 7;

    __shared__ unsigned char Alds[8192];
    __shared__ unsigned char Blds[65536];

    f32x4 acc[4][4] = {};

    const unsigned short* srcA = A_swz + (size_t)(i0 + w * 8 + lrow) * 8192 + k0 + lseg * 8;
    const unsigned short* srcB = cbn_sT + (size_t)(w * 8 + lrow) * 8192 + k0 + lseg * 8;
    const int sw = (c & 7) << 4;

    for (int t = 0; t < 32; ++t) {
        int jt = t * 64;
        gld16(srcA + jt, &Alds[w * 1024]);
        #pragma unroll
        for (int q = 0; q < 8; ++q)
            gld16(srcB + (size_t)(q * 64) * 8192 + jt, &Blds[(q * 64 + w * 8) * 128]);
        asm volatile("s_waitcnt vmcnt(0) lgkmcnt(0)\ns_barrier" ::: "memory");

        #pragma unroll
        for (int kk = 0; kk < 2; ++kk) {
            short8 af[4], bf[4];
            #pragma unroll
            for (int mi = 0; mi < 4; ++mi)
                af[mi] = *reinterpret_cast<const short8*>(
                    &Alds[(mi * 16 + c) * 128 + ((kk * 64 + g * 16) ^ sw)]);
            #pragma unroll
            for (int nn = 0; nn < 4; ++nn)
                bf[nn] = *reinterpret_cast<const short8*>(
                    &Blds[(w * 64 + nn * 16 + c) * 128 + ((kk * 64 + g * 16) ^ sw)]);
            __builtin_amdgcn_s_setprio(1);
            #pragma unroll
            for (int mi = 0; mi < 4; ++mi)
                #pragma unroll
                for (int nn = 0; nn < 4; ++nn)
                    acc[mi][nn] = MFMA16(af[mi], bf[nn], acc[mi][nn]);
            __builtin_amdgcn_s_setprio(0);
        }
        asm volatile("s_waitcnt lgkmcnt(0)\ns_barrier" ::: "memory");
    }

    float* hp = hpart + (size_t)bx * 32768;
    #pragma unroll
    for (int mi = 0; mi < 4; ++mi)
        #pragma unroll
        for (int r = 0; r < 4; ++r) {
            int lr = mi * 16 + g * 4 + r;
            #pragma unroll
            for (int nn = 0; nn < 4; ++nn)
                hp[lr * 512 + w * 64 + nn * 16 + c] = acc[mi][nn][r];
        }
}

// ---- K3b: h = bf16( (Σ_ks hpart) * dinv_i ); 4096 blocks x 256 thr x 4 elems --
__global__ __launch_bounds__(256) void k_reduce(const float* __restrict__ hpart,
                                                const float* __restrict__ dd,
                                                unsigned short* __restrict__ h) {
    size_t flat = ((size_t)blockIdx.x * 256 + threadIdx.x) * 4;
    int i = (int)(flat >> 9), n = (int)(flat & 511);
    int row = i >> 6;
    int local = (i & 63) * 512 + n;
    size_t base = (size_t)(row * 4) * 32768;
    f32x4 v0 = *reinterpret_cast<const f32x4*>(hpart + base + local);
    f32x4 v1 = *reinterpret_cast<const f32x4*>(hpart + base + 32768 + local);
    f32x4 v2 = *reinterpret_cast<const f32x4*>(hpart + base + 2 * 32768 + local);
    f32x4 v3 = *reinterpret_cast<const f32x4*>(hpart + base + 3 * 32768 + local);
    f32x4 sum = (v0 + v1) + (v2 + v3);
    float dinv = rsqrtf(dd[i]);
    ushort4 o;
    o.x = f2bf(sum[0] * dinv);
    o.y = f2bf(sum[1] * dinv);
    o.z = f2bf(sum[2] * dinv);
    o.w = f2bf(sum[3] * dinv);
    *reinterpret_cast<ushort4*>(h + flat) = o;
}

// ---- K4: out = sigmoid(h @ W + b), fp32 out ----------------------------------
__global__ __launch_bounds__(512) void k_out(const unsigned short* __restrict__ h,
                                             const unsigned short* __restrict__ Wt,
                                             const float* __restrict__ b,
                                             float* __restrict__ out) {
    int bx = blockIdx.x;
    int i0 = (bx & 255) * 32, n0 = (bx >> 8) * 256;
    int tid = threadIdx.x;
    int w = tid >> 6, l = tid & 63, g = l >> 4, c = l & 15;
    int wm = w >> 2, wn = w & 3;

    float bb[4];
    #pragma unroll
    for (int nn = 0; nn < 4; ++nn) bb[nn] = b[n0 + wn * 64 + nn * 16 + c];

    f32x4 acc[4] = {};
    for (int k0 = 0; k0 < 512; k0 += 64) {
        short8 af[2];
        #pragma unroll
        for (int kk = 0; kk < 2; ++kk)
            af[kk] = ld8(h + (size_t)(i0 + wm * 16 + c) * 512 + k0 + kk * 32 + g * 8);
        #pragma unroll
        for (int kk = 0; kk < 2; ++kk)
            #pragma unroll
            for (int nn = 0; nn < 4; ++nn) {
                short8 bf = ld8(Wt + (size_t)(n0 + wn * 64 + nn * 16 + c) * 512 + k0 + kk * 32 + g * 8);
                acc[nn] = MFMA16(af[kk], bf, acc[nn]);
            }
    }
    #pragma unroll
    for (int r = 0; r < 4; ++r) {
        int row = i0 + wm * 16 + g * 4 + r;
        #pragma unroll
        for (int nn = 0; nn < 4; ++nn) {
            float z = acc[nn][r] + bb[nn];
            out[(size_t)row * 512 + n0 + wn * 64 + nn * 16 + c] = 1.f / (1.f + exp2f(-1.44269504f * z));
        }
    }
}

extern "C" void kernel_launch(void* const* d_in, const int* in_sizes, int n_in,
                              void* d_out, int out_size, void* d_ws, size_t ws_size,
                              hipStream_t stream) {
    const float* bbn = (const float*)d_in[0];   // [8192, 64]
    const float* cbn = (const float*)d_in[1];   // [8192, 512]
    const float* W   = (const float*)d_in[2];   // [512, 512]
    const float* b   = (const float*)d_in[3];   // [512]
    float* out = (float*)d_out;                 // [8192, 512] fp32

    char* ws = (char*)d_ws;
    unsigned short* bbn_h   = (unsigned short*)(ws);                    // 1 MB
    unsigned short* bbn_swz = (unsigned short*)(ws + (1u << 20));       // 1 MB
    float*          s       = (float*)(ws + (2u << 20));                // 32 KB
    float*          dd      = (float*)(ws + (2u << 20) + (1u << 15));   // 32 KB
    unsigned short* Wt      = (unsigned short*)(ws + (2u << 20) + (2u << 15));  // 512 KB
    unsigned short* cbn_sT  = (unsigned short*)(ws + (3u << 20));       // 8 MB (swizzled, dinv_j-scaled)
    unsigned short* hbuf    = (unsigned short*)(ws + (11u << 20));      // 8 MB
    unsigned short* A_swz   = (unsigned short*)(ws + (19u << 20));      // 128 MB (swizzled adjacency)
    float*          hpart   = (float*)(ws + (147u << 20));              // 64 MB (block-contiguous partials)
    float*          dpart   = (float*)(ws + (211u << 20));              // 4 MB (degree partials [128][8192])

    k_prep_bbn<<<2048, 256, 0, stream>>>(bbn, bbn_h, bbn_swz, s);
    k_transpose_scale<<<64, 256, 0, stream>>>(W, Wt, nullptr, 512, 512, 0);
    k_gen_adj<<<8256, 256, 0, stream>>>(bbn_h, bbn_swz, s, A_swz, dpart);
    k_degree_sum<<<32, 256, 0, stream>>>(dpart, dd);
    k_transpose_scale<<<1024, 256, 0, stream>>>(cbn, cbn_sT, dd, 8192, 512, 1);
    k_spectral<<<512, 512, 0, stream>>>(A_swz, cbn_sT, hpart);
    k_reduce<<<4096, 256, 0, stream>>>(hpart, dd, hbuf);
    k_out<<<512, 512, 0, stream>>>(hbuf, Wt, b, out);
}

// Round 19
// 196.733 us; speedup vs baseline: 1.0094x; 1.0094x over previous
//
#include <hip/hip_runtime.h>
#include <hip/hip_bf16.h>

typedef __attribute__((ext_vector_type(8))) short short8;
typedef __attribute__((ext_vector_type(4))) float f32x4;

#define MFMA16(a, b, c) __builtin_amdgcn_mfma_f32_16x16x32_bf16((a), (b), (c), 0, 0, 0)

__device__ __forceinline__ unsigned short f2bf(float x) {
    union { float f; unsigned int u; } v; v.f = x;
    unsigned int u = v.u;
    return (unsigned short)((u + 0x7FFFu + ((u >> 16) & 1u)) >> 16);
}

__device__ __forceinline__ float pow14(float x) {
    return exp2f(1.4f * log2f(x));
}

__device__ __forceinline__ short8 ld8(const unsigned short* p) {
    return *reinterpret_cast<const short8*>(p);
}

__device__ __forceinline__ void gld16(const void* src, const unsigned char* dst) {
    __builtin_amdgcn_global_load_lds(
        (const __attribute__((address_space(1))) void*)src,
        (__attribute__((address_space(3))) void*)dst, 16, 0, 0);
}

// ---- K0: bbn fp32 -> bf16 (plain + row-swizzled copy), row sums s[i] ---------
__global__ void k_prep_bbn(const float* __restrict__ bbn, unsigned short* __restrict__ bbn_h,
                           unsigned short* __restrict__ bbn_swz, float* __restrict__ s) {
    int row = blockIdx.x * 4 + (threadIdx.x >> 6);
    int lane = threadIdx.x & 63;
    float x = bbn[row * 64 + lane];
    unsigned short h = f2bf(x);
    bbn_h[row * 64 + lane] = h;
    bbn_swz[row * 64 + (lane ^ ((row & 7) << 3))] = h;
    float v = x;
    #pragma unroll
    for (int m = 1; m < 64; m <<= 1) v += __shfl_xor(v, m);
    if (lane == 0) s[row] = v;
}

// ---- K0b/K2: transpose (+optional rsqrt(d) row scale, optional swizzle) ------
__global__ void k_transpose_scale(const float* __restrict__ in, unsigned short* __restrict__ out,
                                  const float* __restrict__ dvec, int K, int N, int swz) {
    __shared__ float tile[64][65];
    int tiles_k = K >> 6;
    int tk = blockIdx.x % tiles_k, tn = blockIdx.x / tiles_k;
    int k0 = tk * 64, n0 = tn * 64;
    int c = threadIdx.x & 63, rq = threadIdx.x >> 6;
    #pragma unroll
    for (int i = 0; i < 16; ++i) {
        int r = rq + 4 * i;
        float sc = dvec ? rsqrtf(dvec[k0 + r]) : 1.0f;
        tile[r][c] = in[(size_t)(k0 + r) * N + n0 + c] * sc;
    }
    __syncthreads();
    #pragma unroll
    for (int i = 0; i < 16; ++i) {
        int r = rq + 4 * i;
        int cc = swz ? (c ^ ((r & 7) << 3)) : c;
        out[(size_t)(n0 + r) * K + k0 + cc] = f2bf(tile[c][r]);
    }
}

// ---- K1: symmetric A materialization + degree partials (r18, verified) --------
__global__ __launch_bounds__(256, 4) void k_gen_adj(const unsigned short* __restrict__ bbn_h,
                                                    const unsigned short* __restrict__ bbn_swz,
                                                    const float* __restrict__ s,
                                                    unsigned short* __restrict__ A_swz,
                                                    float* __restrict__ dpart) {
    int bx = blockIdx.x;
    int ti = (int)((257.0f - sqrtf(66049.0f - 8.0f * (float)bx)) * 0.5f);
    while (ti * (257 - ti) / 2 > bx) --ti;
    while ((ti + 1) * (256 - ti) / 2 <= bx) ++ti;
    int tj = ti + (bx - ti * (257 - ti) / 2);
    int i0 = ti * 64, jbase = tj * 64;

    int tid = threadIdx.x;
    int w = tid >> 6, l = tid & 63, g = l >> 4, c = l & 15;

    __shared__ __align__(16) unsigned char Ajlds[8192];
    __shared__ __align__(16) unsigned char Outlds[8192];
    __shared__ float colbuf[4][64];

    gld16(bbn_swz + (jbase + w * 8 + (l >> 3)) * 64 + (l & 7) * 8, &Ajlds[w * 1024]);
    gld16(bbn_swz + (jbase + 32 + w * 8 + (l >> 3)) * 64 + (l & 7) * 8, &Ajlds[4096 + w * 1024]);

    const unsigned short* ap = bbn_h + (i0 + w * 16 + c) * 64;
    short8 ga0 = ld8(ap), ga1 = ld8(ap + 32);
    float si = s[i0 + w * 16 + c];
    f32x4 sj4_0 = *reinterpret_cast<const f32x4*>(s + jbase + 0 * 16 + g * 4);
    f32x4 sj4_1 = *reinterpret_cast<const f32x4*>(s + jbase + 1 * 16 + g * 4);
    f32x4 sj4_2 = *reinterpret_cast<const f32x4*>(s + jbase + 2 * 16 + g * 4);
    f32x4 sj4_3 = *reinterpret_cast<const f32x4*>(s + jbase + 3 * 16 + g * 4);

    asm volatile("s_waitcnt vmcnt(0) lgkmcnt(0)\ns_barrier" ::: "memory");

    const int sw = (c & 7) << 4;
    float racc = 0.f;

#define GEN_SUB(GJ, SJ4) do {                                                      \
    short8 gb0 = *reinterpret_cast<const short8*>(                                 \
        &Ajlds[((GJ) * 16 + c) * 128 + ((g * 16) ^ sw)]);                          \
    short8 gb1 = *reinterpret_cast<const short8*>(                                 \
        &Ajlds[((GJ) * 16 + c) * 128 + ((64 + g * 16) ^ sw)]);                     \
    f32x4 gf = {0.f, 0.f, 0.f, 0.f};                                               \
    gf = MFMA16(gb0, ga0, gf);                                                     \
    gf = MFMA16(gb1, ga1, gf);                                                     \
    float t0 = fmaf(2.f, gf[0], -(si + (SJ4)[0]));                                 \
    float t1 = fmaf(2.f, gf[1], -(si + (SJ4)[1]));                                 \
    float t2 = fmaf(2.f, gf[2], -(si + (SJ4)[2]));                                 \
    float t3 = fmaf(2.f, gf[3], -(si + (SJ4)[3]));                                 \
    float u0 = pow14(fmaxf(fmaf(fabsf(t0), -0.015625f, 1.f), 0.f));                \
    float u1 = pow14(fmaxf(fmaf(fabsf(t1), -0.015625f, 1.f), 0.f));                \
    float u2 = pow14(fmaxf(fmaf(fabsf(t2), -0.015625f, 1.f), 0.f));                \
    float u3 = pow14(fmaxf(fmaf(fabsf(t3), -0.015625f, 1.f), 0.f));                \
    racc += (u0 + u1) + (u2 + u3);                                                 \
    if (ti != tj) {                                                                \
        float s0 = u0, s1 = u1, s2 = u2, s3 = u3;                                  \
        s0 += __shfl_xor(s0, 1); s0 += __shfl_xor(s0, 2);                          \
        s0 += __shfl_xor(s0, 4); s0 += __shfl_xor(s0, 8);                          \
        s1 += __shfl_xor(s1, 1); s1 += __shfl_xor(s1, 2);                          \
        s1 += __shfl_xor(s1, 4); s1 += __shfl_xor(s1, 8);                          \
        s2 += __shfl_xor(s2, 1); s2 += __shfl_xor(s2, 2);                          \
        s2 += __shfl_xor(s2, 4); s2 += __shfl_xor(s2, 8);                          \
        s3 += __shfl_xor(s3, 1); s3 += __shfl_xor(s3, 2);                          \
        s3 += __shfl_xor(s3, 4); s3 += __shfl_xor(s3, 8);                          \
        if (c == 0) {                                                              \
            f32x4 cs = {s0, s1, s2, s3};                                           \
            *reinterpret_cast<f32x4*>(&colbuf[w][(GJ) * 16 + g * 4]) = cs;         \
        }                                                                          \
    }                                                                              \
    unsigned short p0 = f2bf(u0), p1 = f2bf(u1), p2 = f2bf(u2), p3 = f2bf(u3);     \
    *reinterpret_cast<uint2*>(                                                     \
        &Outlds[(((w * 16 + c) * 128 + ((GJ) * 16 + g * 4) * 2) ^ sw)]) =          \
        make_uint2((unsigned)p0 | ((unsigned)p1 << 16),                            \
                   (unsigned)p2 | ((unsigned)p3 << 16));                           \
} while (0)

    GEN_SUB(0, sj4_0);
    GEN_SUB(1, sj4_1);
    GEN_SUB(2, sj4_2);
    GEN_SUB(3, sj4_3);
#undef GEN_SUB

    racc += __shfl_xor(racc, 16);
    racc += __shfl_xor(racc, 32);
    if (g == 0) dpart[(size_t)tj * 8192 + i0 + w * 16 + c] = racc;

    asm volatile("s_waitcnt lgkmcnt(0)\ns_barrier" ::: "memory");

    if (ti != tj && tid < 64) {
        float v = colbuf[0][tid] + colbuf[1][tid] + colbuf[2][tid] + colbuf[3][tid];
        dpart[(size_t)ti * 8192 + jbase + tid] = v;
    }

    {
        int row = tid >> 2, seg = tid & 3;
        uint4 v0 = *reinterpret_cast<const uint4*>(&Outlds[tid * 32]);
        uint4 v1 = *reinterpret_cast<const uint4*>(&Outlds[tid * 32 + 16]);
        unsigned short* dst = A_swz + (size_t)(i0 + row) * 8192 + jbase + seg * 16;
        *reinterpret_cast<uint4*>(dst) = v0;
        *reinterpret_cast<uint4*>(dst + 8) = v1;
    }
    if (ti != tj) {
        int jt = tid >> 2, grp = tid & 3;
        int Xj = (jt & 7) << 3;
        #pragma unroll
        for (int hh = 0; hh < 2; ++hh) {
            unsigned short vv[8];
            #pragma unroll
            for (int e = 0; e < 8; ++e) {
                int it = grp * 16 + hh * 8 + e;
                vv[e] = *reinterpret_cast<const unsigned short*>(
                    &Outlds[it * 128 + ((jt * 2) ^ ((it & 7) << 4))]);
            }
            uint4 pk = make_uint4(
                (unsigned)vv[0] | ((unsigned)vv[1] << 16),
                (unsigned)vv[2] | ((unsigned)vv[3] << 16),
                (unsigned)vv[4] | ((unsigned)vv[5] << 16),
                (unsigned)vv[6] | ((unsigned)vv[7] << 16));
            *reinterpret_cast<uint4*>(
                A_swz + (size_t)(jbase + jt) * 8192 + i0 + ((grp * 16 + hh * 8) ^ Xj)) = pk;
        }
    }
}

// ---- K1b: d[i] = sum over 128 contributors of dpart[c][i] --------------------
__global__ __launch_bounds__(256) void k_degree_sum(const float* __restrict__ dpart,
                                                    float* __restrict__ dd) {
    int i = blockIdx.x * 256 + threadIdx.x;
    float v = 0.f;
    for (int cb = 0; cb < 128; ++cb) v += dpart[(size_t)cb * 8192 + i];
    dd[i] = v;
}

// ---- K3: split-K GEMM, BM=64 x BN=512, Ksplit=4; 4 waves x (64x128)/wave ------
// 256 thr; A-frag LDS-read duplication drops 8x->4x (200->168 KB/iter total
// LDS traffic vs r18's 8-wave 64x64); 64 MFMA per wave per iter (more ILP).
// acc 4x8 f32x4 = 128 VGPR; launch_bounds(256,2) -> cap 256 VGPR, no spill.
// LDS 72KB single-buffered -> 2 blocks/CU to hide the vmcnt(0) drain.
__global__ __launch_bounds__(256, 2) void k_spectral(const unsigned short* __restrict__ A_swz,
                                                     const unsigned short* __restrict__ cbn_sT,
                                                     float* __restrict__ hpart) {
    int bx = blockIdx.x;
    int row = bx >> 2, ks = bx & 3;
    int i0 = row * 64, k0 = ks * 2048;

    int tid = threadIdx.x;
    int w = tid >> 6, l = tid & 63, g = l >> 4, c = l & 15;
    int lrow = l >> 3, lseg = l & 7;

    __shared__ unsigned char Alds[8192];
    __shared__ unsigned char Blds[65536];

    f32x4 acc[4][8] = {};

    const unsigned short* srcA = A_swz + (size_t)(i0 + w * 16 + lrow) * 8192 + k0 + lseg * 8;
    const unsigned short* srcB = cbn_sT + (size_t)(w * 128 + lrow) * 8192 + k0 + lseg * 8;
    const int sw = (c & 7) << 4;

    for (int t = 0; t < 32; ++t) {
        int jt = t * 64;
        // A: wave w stages rows w*16..w*16+15 (2 insts)
        gld16(srcA + jt, &Alds[w * 2048]);
        gld16(srcA + (size_t)8 * 8192 + jt, &Alds[w * 2048 + 1024]);
        // B: wave w stages rows w*128..w*128+127 (16 insts)
        #pragma unroll
        for (int q = 0; q < 16; ++q)
            gld16(srcB + (size_t)(q * 8) * 8192 + jt, &Blds[(w * 128 + q * 8) * 128]);
        asm volatile("s_waitcnt vmcnt(0) lgkmcnt(0)\ns_barrier" ::: "memory");

        #pragma unroll
        for (int kk = 0; kk < 2; ++kk) {
            short8 af[4], bf[8];
            #pragma unroll
            for (int mi = 0; mi < 4; ++mi)
                af[mi] = *reinterpret_cast<const short8*>(
                    &Alds[(mi * 16 + c) * 128 + ((kk * 64 + g * 16) ^ sw)]);
            #pragma unroll
            for (int nn = 0; nn < 8; ++nn)
                bf[nn] = *reinterpret_cast<const short8*>(
                    &Blds[(w * 128 + nn * 16 + c) * 128 + ((kk * 64 + g * 16) ^ sw)]);
            __builtin_amdgcn_s_setprio(1);
            #pragma unroll
            for (int mi = 0; mi < 4; ++mi)
                #pragma unroll
                for (int nn = 0; nn < 8; ++nn)
                    acc[mi][nn] = MFMA16(af[mi], bf[nn], acc[mi][nn]);
            __builtin_amdgcn_s_setprio(0);
        }
        asm volatile("s_waitcnt lgkmcnt(0)\ns_barrier" ::: "memory");
    }

    // epilogue: block-contiguous 128KB fp32 partial tile (64 rows x 512 cols)
    float* hp = hpart + (size_t)bx * 32768;
    #pragma unroll
    for (int mi = 0; mi < 4; ++mi)
        #pragma unroll
        for (int r = 0; r < 4; ++r) {
            int lr = mi * 16 + g * 4 + r;
            #pragma unroll
            for (int nn = 0; nn < 8; ++nn)
                hp[lr * 512 + w * 128 + nn * 16 + c] = acc[mi][nn][r];
        }
}

// ---- K3b: h = bf16( (Σ_ks hpart) * dinv_i ); 4096 blocks x 256 thr x 4 elems --
__global__ __launch_bounds__(256) void k_reduce(const float* __restrict__ hpart,
                                                const float* __restrict__ dd,
                                                unsigned short* __restrict__ h) {
    size_t flat = ((size_t)blockIdx.x * 256 + threadIdx.x) * 4;
    int i = (int)(flat >> 9), n = (int)(flat & 511);
    int row = i >> 6;
    int local = (i & 63) * 512 + n;
    size_t base = (size_t)(row * 4) * 32768;
    f32x4 v0 = *reinterpret_cast<const f32x4*>(hpart + base + local);
    f32x4 v1 = *reinterpret_cast<const f32x4*>(hpart + base + 32768 + local);
    f32x4 v2 = *reinterpret_cast<const f32x4*>(hpart + base + 2 * 32768 + local);
    f32x4 v3 = *reinterpret_cast<const f32x4*>(hpart + base + 3 * 32768 + local);
    f32x4 sum = (v0 + v1) + (v2 + v3);
    float dinv = rsqrtf(dd[i]);
    ushort4 o;
    o.x = f2bf(sum[0] * dinv);
    o.y = f2bf(sum[1] * dinv);
    o.z = f2bf(sum[2] * dinv);
    o.w = f2bf(sum[3] * dinv);
    *reinterpret_cast<ushort4*>(h + flat) = o;
}

// ---- K4: out = sigmoid(h @ W + b), fp32 out ----------------------------------
__global__ __launch_bounds__(512) void k_out(const unsigned short* __restrict__ h,
                                             const unsigned short* __restrict__ Wt,
                                             const float* __restrict__ b,
                                             float* __restrict__ out) {
    int bx = blockIdx.x;
    int i0 = (bx & 255) * 32, n0 = (bx >> 8) * 256;
    int tid = threadIdx.x;
    int w = tid >> 6, l = tid & 63, g = l >> 4, c = l & 15;
    int wm = w >> 2, wn = w & 3;

    float bb[4];
    #pragma unroll
    for (int nn = 0; nn < 4; ++nn) bb[nn] = b[n0 + wn * 64 + nn * 16 + c];

    f32x4 acc[4] = {};
    for (int k0 = 0; k0 < 512; k0 += 64) {
        short8 af[2];
        #pragma unroll
        for (int kk = 0; kk < 2; ++kk)
            af[kk] = ld8(h + (size_t)(i0 + wm * 16 + c) * 512 + k0 + kk * 32 + g * 8);
        #pragma unroll
        for (int kk = 0; kk < 2; ++kk)
            #pragma unroll
            for (int nn = 0; nn < 4; ++nn) {
                short8 bf = ld8(Wt + (size_t)(n0 + wn * 64 + nn * 16 + c) * 512 + k0 + kk * 32 + g * 8);
                acc[nn] = MFMA16(af[kk], bf, acc[nn]);
            }
    }
    #pragma unroll
    for (int r = 0; r < 4; ++r) {
        int row = i0 + wm * 16 + g * 4 + r;
        #pragma unroll
        for (int nn = 0; nn < 4; ++nn) {
            float z = acc[nn][r] + bb[nn];
            out[(size_t)row * 512 + n0 + wn * 64 + nn * 16 + c] = 1.f / (1.f + exp2f(-1.44269504f * z));
        }
    }
}

extern "C" void kernel_launch(void* const* d_in, const int* in_sizes, int n_in,
                              void* d_out, int out_size, void* d_ws, size_t ws_size,
                              hipStream_t stream) {
    const float* bbn = (const float*)d_in[0];   // [8192, 64]
    const float* cbn = (const float*)d_in[1];   // [8192, 512]
    const float* W   = (const float*)d_in[2];   // [512, 512]
    const float* b   = (const float*)d_in[3];   // [512]
    float* out = (float*)d_out;                 // [8192, 512] fp32

    char* ws = (char*)d_ws;
    unsigned short* bbn_h   = (unsigned short*)(ws);                    // 1 MB
    unsigned short* bbn_swz = (unsigned short*)(ws + (1u << 20));       // 1 MB
    float*          s       = (float*)(ws + (2u << 20));                // 32 KB
    float*          dd      = (float*)(ws + (2u << 20) + (1u << 15));   // 32 KB
    unsigned short* Wt      = (unsigned short*)(ws + (2u << 20) + (2u << 15));  // 512 KB
    unsigned short* cbn_sT  = (unsigned short*)(ws + (3u << 20));       // 8 MB (swizzled, dinv_j-scaled)
    unsigned short* hbuf    = (unsigned short*)(ws + (11u << 20));      // 8 MB
    unsigned short* A_swz   = (unsigned short*)(ws + (19u << 20));      // 128 MB (swizzled adjacency)
    float*          hpart   = (float*)(ws + (147u << 20));              // 64 MB (block-contiguous partials)
    float*          dpart   = (float*)(ws + (211u << 20));              // 4 MB (degree partials [128][8192])

    k_prep_bbn<<<2048, 256, 0, stream>>>(bbn, bbn_h, bbn_swz, s);
    k_transpose_scale<<<64, 256, 0, stream>>>(W, Wt, nullptr, 512, 512, 0);
    k_gen_adj<<<8256, 256, 0, stream>>>(bbn_h, bbn_swz, s, A_swz, dpart);
    k_degree_sum<<<32, 256, 0, stream>>>(dpart, dd);
    k_transpose_scale<<<1024, 256, 0, stream>>>(cbn, cbn_sT, dd, 8192, 512, 1);
    k_spectral<<<512, 256, 0, stream>>>(A_swz, cbn_sT, hpart);
    k_reduce<<<4096, 256, 0, stream>>>(hpart, dd, hbuf);
    k_out<<<512, 512, 0, stream>>>(hbuf, Wt, b, out);
}